// Round 4
// baseline (204.052 us; speedup 1.0000x reference)
//
#include <hip/hip_runtime.h>
#include <hip/hip_bf16.h>
#include <hip/hip_fp16.h>
#include <math.h>

// Problem constants (B,S,H,M) = (8,128,768,128)
#define B_   8
#define S_   128
#define H_   768
#define M_   128
#define P_   8256      // S*(S+1)/2 pairs per batch
#define BP_  66048     // B_ * P_
#define EPSF 1e-12f

typedef unsigned short u16;
typedef unsigned int   u32;
typedef _Float16 h16;
typedef _Float16 ffrag __attribute__((ext_vector_type(8)));   // 8 f16 = 4 VGPR
typedef float    f32x4 __attribute__((ext_vector_type(4)));

// packed f16 fma: one v_pk_fma_f16 for two lanes
__device__ __forceinline__ u32 fuse2(u32 x, u32 g, u32 b) {
    __half2 r = __hfma2(__builtin_bit_cast(__half2, x),
                        __builtin_bit_cast(__half2, g),
                        __builtin_bit_cast(__half2, b));
    return __builtin_bit_cast(u32, r);
}
// tanh(x) = 1 - 2/(e^{2x}+1): exp + rcp + fma, branch/copysign-free,
// correct at +-inf (rcp(inf)=0 -> 1; exp(-inf)=0 -> -1)
__device__ __forceinline__ float fast_tanh(float v) {
    float t = __expf(v + v);
    float r = __builtin_amdgcn_rcpf(t + 1.0f);
    return fmaf(-2.0f, r, 1.0f);
}
// async global->LDS 16B per lane; lds dst must be the wave-uniform base
__device__ __forceinline__ void gl_lds16(const h16* g, h16* l) {
    __builtin_amdgcn_global_load_lds(
        (const __attribute__((address_space(1))) u32*)g,
        (__attribute__((address_space(3))) u32*)l, 16, 0, 0);
}

// ============ kernel A: weight convert + B-prepack + per-row normalize ============
// blocks [0,5763): convert fp32 weights -> f16:
//   [0,589824)          wgb  = w_gamma f16
//   [589824,1179648)    wbb  = w_beta  f16
//   [1179648,1474560)   wpk  = pre-packed pair-GEMM B tiles, BN=128:
//                       wpk[nb][kt][ch][n][e] = w_nb[(kt*64+ch*8+e)*128 + n]
//                       (16KB contiguous image per (nb,kt), exact LDS slot
//                       order -> pair-GEMM B DMA fully coalesced)
//   [1474560,1474944)   biasc
// blocks [5763, 5763+1024): row normalize; xn = (x-mean)/(var+eps)^2
#define NORM0 5763
__global__ void k_prep(const float* __restrict__ seq,
                       const float* __restrict__ wg, const float* __restrict__ wb,
                       const float* __restrict__ we, const float* __restrict__ wh,
                       const float* __restrict__ wt,
                       const float* __restrict__ be, const float* __restrict__ bh,
                       const float* __restrict__ bt,
                       h16* __restrict__ wgb, h16* __restrict__ wbb,
                       h16* __restrict__ wpk, float* __restrict__ biasc,
                       h16* __restrict__ xn, h16* __restrict__ condb)
{
    __shared__ float red[4];
    const int bx = blockIdx.x;
    const int t = threadIdx.x;

    if (bx < NORM0) {   // ---- convert / pre-pack ----
        int idx = bx * 256 + t;
        if (idx < 589824) {
            wgb[idx] = (h16)wg[idx];
        } else if (idx < 1179648) {
            int i = idx - 589824;
            wbb[i] = (h16)wb[i];
        } else if (idx < 1474560) {
            int i = idx - 1179648;             // wpk[nb][kt][ch][n][e]
            int e  = i & 7;
            int n  = (i >> 3) & 127;
            int v  = i >> 10;                  // [0,288)
            int ch = v & 7;
            int w2 = v >> 3;                   // [0,36)
            int kt = w2 % 12;
            int nb = w2 / 12;
            int h  = kt * 64 + ch * 8 + e;     // global k
            const float* src = (nb == 0) ? we : (nb == 1 ? wh : wt);
            wpk[i] = (h16)src[h * 128 + n];
        } else if (idx < 1474944) {
            int n = idx - 1474560;
            biasc[n] = (n < 128) ? be[n] : (n < 256 ? bh[n - 128] : bt[n - 256]);
        }
        return;
    }
    // ---- normalize ----
    const int row = bx - NORM0;
    const int lane = t & 63, wid = t >> 6;
    const float* x = seq + (size_t)row * H_;
    float x0 = x[t], x1 = x[t + 256], x2 = x[t + 512];

    float s = x0 + x1 + x2;
    for (int o = 32; o; o >>= 1) s += __shfl_xor(s, o);
    if (lane == 0) red[wid] = s;
    __syncthreads();
    float mean = (red[0] + red[1] + red[2] + red[3]) * (1.0f / 768.0f);

    float c0 = x0 - mean, c1 = x1 - mean, c2 = x2 - mean;
    float ss = c0 * c0 + c1 * c1 + c2 * c2;
    for (int o = 32; o; o >>= 1) ss += __shfl_xor(ss, o);
    __syncthreads();
    if (lane == 0) red[wid] = ss;
    __syncthreads();
    float var = (red[0] + red[1] + red[2] + red[3]) * (1.0f / 768.0f);
    float sd = var + EPSF;
    float scale = 1.0f / (sd * sd);

    h16* xr = xn + (size_t)row * H_;
    h16* cr = condb + (size_t)row * H_;
    xr[t] = (h16)(c0 * scale); xr[t + 256] = (h16)(c1 * scale); xr[t + 512] = (h16)(c2 * scale);
    cr[t] = (h16)x0;           cr[t + 256] = (h16)x1;           cr[t + 512] = (h16)x2;
}

// ============ kernel B: cond GEMM -> gamma_c / beta_c (f16) ============
// C[p][o] = sum_h cond[p][h] * W[o][h] + bias[o];  tiles 64x64, BK=64
// grid (16, 24): by<12 -> gamma cols by*64 ; else beta cols (by-12)*64
// LDS stride 72 h16 = 144 B: addr%128 takes 8 values over 16 rows -> conflict-free
__global__ __launch_bounds__(256) void k_cond_gemm(
    const h16* __restrict__ Ab, const h16* __restrict__ Wg, const h16* __restrict__ Wb,
    const float* __restrict__ gamma, const float* __restrict__ beta,
    h16* __restrict__ Gc, h16* __restrict__ Bc)
{
    __shared__ h16 Ash[64 * 72];
    __shared__ h16 Bsh[64 * 72];
    const int t = threadIdx.x;
    const int row0 = blockIdx.x * 64;
    const int by = blockIdx.y;
    const bool isg = (by < 12);
    const int nc0 = (isg ? by : by - 12) * 64;
    const h16* wsrc = isg ? Wg : Wb;

    const int r = t >> 2, q = t & 3;
    const h16* ap = Ab + (size_t)(row0 + r) * H_ + q * 16;
    const h16* wp = wsrc + (size_t)(nc0 + r) * H_ + q * 16;
    h16* asto = &Ash[r * 72 + q * 16];
    h16* bsto = &Bsh[r * 72 + q * 16];

    const int lane = t & 63, wid = t >> 6;
    const int wm0 = (wid >> 1) * 32, wn0 = (wid & 1) * 32;
    const int l15 = lane & 15, quad = lane >> 4, q8 = quad * 8;

    f32x4 acc[2][2] = {};
    for (int kt = 0; kt < 12; ++kt) {
        const int k0 = kt * 64;
        uint4 a0 = *(const uint4*)(ap + k0); uint4 a1 = *(const uint4*)(ap + k0 + 8);
        uint4 w0 = *(const uint4*)(wp + k0); uint4 w1 = *(const uint4*)(wp + k0 + 8);
        *(uint4*)asto = a0; *(uint4*)(asto + 8) = a1;
        *(uint4*)bsto = w0; *(uint4*)(bsto + 8) = w1;
        __syncthreads();
#pragma unroll
        for (int ks = 0; ks < 64; ks += 32) {
            ffrag af[2], bf[2];
#pragma unroll
            for (int mi = 0; mi < 2; ++mi)
                af[mi] = *reinterpret_cast<const ffrag*>(&Ash[(wm0 + mi * 16 + l15) * 72 + ks + q8]);
#pragma unroll
            for (int ni = 0; ni < 2; ++ni)
                bf[ni] = *reinterpret_cast<const ffrag*>(&Bsh[(wn0 + ni * 16 + l15) * 72 + ks + q8]);
#pragma unroll
            for (int mi = 0; mi < 2; ++mi)
#pragma unroll
                for (int ni = 0; ni < 2; ++ni)
                    acc[mi][ni] = __builtin_amdgcn_mfma_f32_16x16x32_f16(af[mi], bf[ni], acc[mi][ni], 0, 0, 0);
        }
        __syncthreads();
    }

    const float* bias = isg ? gamma : beta;
    h16* outp = isg ? Gc : Bc;
#pragma unroll
    for (int mi = 0; mi < 2; ++mi)
#pragma unroll
        for (int ni = 0; ni < 2; ++ni) {
            int c = wn0 + ni * 16 + l15;
            float bv = bias[nc0 + c];
#pragma unroll
            for (int reg = 0; reg < 4; ++reg) {
                int rg = wm0 + mi * 16 + quad * 4 + reg;   // C/D: col=lane&15, row=quad*4+reg (m89)
                outp[(size_t)(row0 + rg) * H_ + nc0 + c] = (h16)(acc[mi][ni][reg] + bv);
            }
        }
}

// ============ kernel C: fused pair GEMM ============
// out[head, gp, m] = tanh( (xn[b,j]*gc[b,i] + bc[b,i]) @ W[:, cg] + biasc[cg] )
// v5 (T3+T4 counted-vmcnt pipeline): Block 128x128, BK=64, 12 iters.
// r3 post-mortem: time/iter tracks WORK/iter (v3->v4: 1.32x vs 1.33x) ->
// phases SUM instead of overlap (m233 2-phase stall). Fix: never drain
// vmcnt in the main loop.  B triple-buffered, DMA'd 2 iters ahead (issued
// right after the barrier, when its buffer's last readers are done).
// Barrier = s_waitcnt lgkmcnt(0) + raw s_barrier (NO vmem drain).
// DMA(k) completion before its ds_reads is guaranteed transitively:
// A-loads(k) are issued AFTER DMA(k) (pinned by sched_barrier), and the
// compiler's register-wait for A(k) at iter k-1's fuse retires the older
// DMA(k) via in-order vmcnt, one full iter + barrier before Bsh[k%3] is
// read.  T5: setprio(1) around the MFMA cluster.
// LDS: A 2x16KB + B 3x16KB = 80 KB -> 2 blocks/CU.
__global__ __launch_bounds__(256, 2) void k_pair_gemm(
    const h16* __restrict__ Xn, const h16* __restrict__ Gcb, const h16* __restrict__ Bcb,
    const h16* __restrict__ Wpk, const float* __restrict__ biasc,
    float* __restrict__ out)
{
    __shared__ h16 Ash[2][8 * 128 * 8];   // 16 KB per buf
    __shared__ h16 Bsh[3][8 * 128 * 8];   // 16 KB per buf, triple

    const int t = threadIdx.x;
    const int row0 = blockIdx.x * 128;
    const int nb = blockIdx.y;            // 0..2 -> cols nb*128

    // ---- per-thread staging-row decode (row r_s, k-half `half`) ----
    const int r_s = t >> 1, half = t & 1;
    int gp = row0 + r_s;
    int b = gp / P_;
    int p = gp - b * P_;
    int i = (int)((257.0f - sqrtf(66049.0f - 8.0f * (float)p)) * 0.5f);
    if (i < 0) i = 0; if (i > 127) i = 127;
    while (i > 0 && (i * (257 - i)) / 2 > p) --i;
    while (((i + 1) * (256 - i)) / 2 <= p) ++i;
    int j = i + (p - (i * (257 - i)) / 2);

    const h16* xp  = Xn  + (size_t)(b * 128 + j) * H_ + half * 32;
    const h16* gp_ = Gcb + (size_t)(b * 128 + i) * H_ + half * 32;
    const h16* bp_ = Bcb + (size_t)(b * 128 + i) * H_ + half * 32;
    int aw[4];
#pragma unroll
    for (int u = 0; u < 4; ++u)
        aw[u] = ((half * 4 + u) * 128 + r_s) * 8;

    // B DMA: prepacked tile for (nb,kt) is 8192 h16 contiguous, slot order
    const h16* wtile = Wpk + (size_t)nb * 12 * 8192;
    const int wud = t & ~63;              // wave-uniform slot base

    const int lane = t & 63, wid = t >> 6;
    const int wm0 = (wid >> 1) * 64, wn0 = (wid & 1) * 64;
    const int l15 = lane & 15, quad = lane >> 4;

    uint4 xa[4], ga[4], ba[4];

    // ---------- prologue ----------
    // A(0) loads -> fuse -> Ash[0]
#pragma unroll
    for (int u = 0; u < 4; ++u) {
        xa[u] = *(const uint4*)(xp + u * 8);
        ga[u] = *(const uint4*)(gp_ + u * 8);
        ba[u] = *(const uint4*)(bp_ + u * 8);
    }
#pragma unroll
    for (int u = 0; u < 4; ++u) {
        uint4 f;
        f.x = fuse2(xa[u].x, ga[u].x, ba[u].x); f.y = fuse2(xa[u].y, ga[u].y, ba[u].y);
        f.z = fuse2(xa[u].z, ga[u].z, ba[u].z); f.w = fuse2(xa[u].w, ga[u].w, ba[u].w);
        *(uint4*)&Ash[0][aw[u]] = f;
    }
    // DMA B(0) -> Bsh[0], B(1) -> Bsh[1]
#pragma unroll
    for (int c = 0; c < 4; ++c)
        gl_lds16(wtile + (size_t)(c * 256 + t) * 8, &Bsh[0][(c * 256 + wud) * 8]);
#pragma unroll
    for (int c = 0; c < 4; ++c)
        gl_lds16(wtile + 8192 + (size_t)(c * 256 + t) * 8, &Bsh[1][(c * 256 + wud) * 8]);
    __builtin_amdgcn_sched_barrier(0);    // keep A(1) issue AFTER the DMAs
    // A(1) loads (consumed at iter0's fuse; that wait retires DMA(0),DMA(1))
#pragma unroll
    for (int u = 0; u < 4; ++u) {
        xa[u] = *(const uint4*)(xp + 64 + u * 8);
        ga[u] = *(const uint4*)(gp_ + 64 + u * 8);
        ba[u] = *(const uint4*)(bp_ + 64 + u * 8);
    }
    asm volatile("s_waitcnt lgkmcnt(0)" ::: "memory");
    __builtin_amdgcn_s_barrier();

    f32x4 acc[4][4] = {};
    int bcur = 0, bpre = 2;               // Bbuf of kt%3 and (kt+2)%3
    for (int kt = 0; kt < 12; ++kt) {
        // phase 1: DMA B(kt+2) into Bsh[(kt+2)%3] (its readers finished
        // before the barrier we just crossed)
        if (kt < 10) {
            const h16* wnext = wtile + (size_t)(kt + 2) * 8192;
#pragma unroll
            for (int c = 0; c < 4; ++c)
                gl_lds16(wnext + (size_t)(c * 256 + t) * 8, &Bsh[bpre][(c * 256 + wud) * 8]);
        }
        __builtin_amdgcn_sched_barrier(0);  // pin: A(kt+2) issues AFTER DMA(kt+2)
        // phase 2: fuse A(kt+1) (reg-wait here transitively retires DMA(kt+1))
        if (kt < 11) {
            const int abn = (kt + 1) & 1;
#pragma unroll
            for (int u = 0; u < 4; ++u) {
                uint4 f;
                f.x = fuse2(xa[u].x, ga[u].x, ba[u].x); f.y = fuse2(xa[u].y, ga[u].y, ba[u].y);
                f.z = fuse2(xa[u].z, ga[u].z, ba[u].z); f.w = fuse2(xa[u].w, ga[u].w, ba[u].w);
                *(uint4*)&Ash[abn][aw[u]] = f;
            }
        }
        // phase 3: issue A(kt+2) loads
        if (kt < 10) {
            const int k0 = (kt + 2) * 64;
#pragma unroll
            for (int u = 0; u < 4; ++u) {
                xa[u] = *(const uint4*)(xp + k0 + u * 8);
                ga[u] = *(const uint4*)(gp_ + k0 + u * 8);
                ba[u] = *(const uint4*)(bp_ + k0 + u * 8);
            }
        }
        __builtin_amdgcn_sched_barrier(0);
        // phase 4: fragments + MFMA
        {
            const int ab = kt & 1;
            __builtin_amdgcn_s_setprio(1);
#pragma unroll
            for (int ks = 0; ks < 64; ks += 32) {
                const int ch0 = ks >> 3;      // 0 or 4
                ffrag af[4], bf[4];
#pragma unroll
                for (int mi = 0; mi < 4; ++mi)
                    af[mi] = *reinterpret_cast<const ffrag*>(
                        &Ash[ab][((ch0 + quad) * 128 + wm0 + mi * 16 + l15) * 8]);
#pragma unroll
                for (int ni = 0; ni < 4; ++ni)
                    bf[ni] = *reinterpret_cast<const ffrag*>(
                        &Bsh[bcur][((ch0 + quad) * 128 + wn0 + ni * 16 + l15) * 8]);
#pragma unroll
                for (int mi = 0; mi < 4; ++mi)
#pragma unroll
                    for (int ni = 0; ni < 4; ++ni)
                        acc[mi][ni] = __builtin_amdgcn_mfma_f32_16x16x32_f16(af[mi], bf[ni], acc[mi][ni], 0, 0, 0);
            }
            __builtin_amdgcn_s_setprio(0);
        }
        bcur = (bcur == 2) ? 0 : bcur + 1;
        bpre = (bpre == 2) ? 0 : bpre + 1;
        if (kt < 11) {
            // NO vmem drain: only LDS visibility (ds_writes of phase 2)
            asm volatile("s_waitcnt lgkmcnt(0)" ::: "memory");
            __builtin_amdgcn_s_barrier();
        }
    }

    // epilogue: bias + tanh + store (head == nb, m == col, since BN=128)
#pragma unroll
    for (int mi = 0; mi < 4; ++mi)
#pragma unroll
        for (int ni = 0; ni < 4; ++ni) {
            int c = wn0 + ni * 16 + l15;
            float bv = biasc[nb * 128 + c];
#pragma unroll
            for (int reg = 0; reg < 4; ++reg) {
                int rg = wm0 + mi * 16 + quad * 4 + reg;
                out[((size_t)nb * BP_ + row0 + rg) * M_ + c] = fast_tanh(acc[mi][ni][reg] + bv);
            }
        }
}

extern "C" void kernel_launch(void* const* d_in, const int* in_sizes, int n_in,
                              void* d_out, int out_size, void* d_ws, size_t ws_size,
                              hipStream_t stream)
{
    const float* seq     = (const float*)d_in[0];
    const float* gamma   = (const float*)d_in[1];
    const float* beta    = (const float*)d_in[2];
    const float* w_beta  = (const float*)d_in[3];
    const float* w_gamma = (const float*)d_in[4];
    const float* w_ent   = (const float*)d_in[5];
    const float* b_ent   = (const float*)d_in[6];
    const float* w_head  = (const float*)d_in[7];
    const float* b_head  = (const float*)d_in[8];
    const float* w_tail  = (const float*)d_in[9];
    const float* b_tail  = (const float*)d_in[10];
    float* out = (float*)d_out;

    // workspace layout (all 16B-aligned)
    char* ws = (char*)d_ws;
    h16* xn    = (h16*)ws; ws += (size_t)1024 * 768 * 2;  // normalized rows, f16
    h16* condb = (h16*)ws; ws += (size_t)1024 * 768 * 2;  // seq as f16
    h16* wgb   = (h16*)ws; ws += (size_t)768 * 768 * 2;   // w_gamma f16 [o][h]
    h16* wbb   = (h16*)ws; ws += (size_t)768 * 768 * 2;   // w_beta  f16 [o][h]
    h16* wpk   = (h16*)ws; ws += (size_t)294912 * 2;      // pre-packed B tiles (3 x 12 x 16KB)
    h16* gc    = (h16*)ws; ws += (size_t)1024 * 768 * 2;  // gamma_c f16
    h16* bc    = (h16*)ws; ws += (size_t)1024 * 768 * 2;  // beta_c  f16
    float* biasc = (float*)ws; ws += 384 * 4;             // [ent|head|tail] bias

    hipLaunchKernelGGL(k_prep, dim3(NORM0 + 1024), dim3(256), 0, stream,
                       seq, w_gamma, w_beta, w_ent, w_head, w_tail,
                       b_ent, b_head, b_tail, wgb, wbb, wpk, biasc, xn, condb);
    hipLaunchKernelGGL(k_cond_gemm, dim3(16, 24), dim3(256), 0, stream,
                       condb, wgb, wbb, gamma, beta, gc, bc);
    hipLaunchKernelGGL(k_pair_gemm, dim3(516, 3), dim3(256), 0, stream,
                       xn, gc, bc, wpk, biasc, out);
}

// Round 5
// 198.218 us; speedup vs baseline: 1.0294x; 1.0294x over previous
//
#include <hip/hip_runtime.h>
#include <hip/hip_bf16.h>
#include <hip/hip_fp16.h>
#include <math.h>

// Problem constants (B,S,H,M) = (8,128,768,128)
#define B_   8
#define S_   128
#define H_   768
#define M_   128
#define P_   8256      // S*(S+1)/2 pairs per batch
#define BP_  66048     // B_ * P_
#define EPSF 1e-12f

typedef unsigned short u16;
typedef unsigned int   u32;
typedef _Float16 h16;
typedef _Float16 ffrag __attribute__((ext_vector_type(8)));   // 8 f16 = 4 VGPR
typedef float    f32x16 __attribute__((ext_vector_type(16))); // 32x32 MFMA acc

// packed f16 fma: one v_pk_fma_f16 for two lanes
__device__ __forceinline__ u32 fuse2(u32 x, u32 g, u32 b) {
    __half2 r = __hfma2(__builtin_bit_cast(__half2, x),
                        __builtin_bit_cast(__half2, g),
                        __builtin_bit_cast(__half2, b));
    return __builtin_bit_cast(u32, r);
}
// tanh(x) = 1 - 2/(e^{2x}+1): exp + rcp + fma, branch/copysign-free,
// correct at +-inf (rcp(inf)=0 -> 1; exp(-inf)=0 -> -1)
__device__ __forceinline__ float fast_tanh(float v) {
    float t = __expf(v + v);
    float r = __builtin_amdgcn_rcpf(t + 1.0f);
    return fmaf(-2.0f, r, 1.0f);
}
// async global->LDS 16B per lane; lds dst must be the wave-uniform base
__device__ __forceinline__ void gl_lds16(const h16* g, h16* l) {
    __builtin_amdgcn_global_load_lds(
        (const __attribute__((address_space(1))) u32*)g,
        (__attribute__((address_space(3))) u32*)l, 16, 0, 0);
}

// ============ kernel A: weight convert + B-prepack + per-row normalize ============
// blocks [0,5763): convert fp32 weights -> f16:
//   [0,589824)          wgb  = w_gamma f16
//   [589824,1179648)    wbb  = w_beta  f16
//   [1179648,1474560)   wpk  = pre-packed pair-GEMM B tiles, BN=128, BK=32:
//                       wpk[nb][kt24][ch4][n128][e8] = w_nb[(kt*32+ch*8+e)*128+n]
//                       (8KB contiguous image per (nb,kt), exact LDS slot
//                       order -> pair-GEMM B DMA fully coalesced)
//   [1474560,1474944)   biasc
// blocks [5763, 5763+1024): row normalize; xn = (x-mean)/(var+eps)^2
#define NORM0 5763
__global__ void k_prep(const float* __restrict__ seq,
                       const float* __restrict__ wg, const float* __restrict__ wb,
                       const float* __restrict__ we, const float* __restrict__ wh,
                       const float* __restrict__ wt,
                       const float* __restrict__ be, const float* __restrict__ bh,
                       const float* __restrict__ bt,
                       h16* __restrict__ wgb, h16* __restrict__ wbb,
                       h16* __restrict__ wpk, float* __restrict__ biasc,
                       h16* __restrict__ xn, h16* __restrict__ condb)
{
    __shared__ float red[4];
    const int bx = blockIdx.x;
    const int t = threadIdx.x;

    if (bx < NORM0) {   // ---- convert / pre-pack ----
        int idx = bx * 256 + t;
        if (idx < 589824) {
            wgb[idx] = (h16)wg[idx];
        } else if (idx < 1179648) {
            int i = idx - 589824;
            wbb[i] = (h16)wb[i];
        } else if (idx < 1474560) {
            int i = idx - 1179648;             // wpk[nb][kt][ch][n][e]
            int e  = i & 7;
            int n  = (i >> 3) & 127;
            int v  = i >> 10;                  // [0,288)
            int ch = v & 3;
            int w2 = v >> 2;                   // [0,72)
            int kt = w2 % 24;
            int nb = w2 / 24;
            int h  = kt * 32 + ch * 8 + e;     // global k
            const float* src = (nb == 0) ? we : (nb == 1 ? wh : wt);
            wpk[i] = (h16)src[h * 128 + n];
        } else if (idx < 1474944) {
            int n = idx - 1474560;
            biasc[n] = (n < 128) ? be[n] : (n < 256 ? bh[n - 128] : bt[n - 256]);
        }
        return;
    }
    // ---- normalize ----
    const int row = bx - NORM0;
    const int lane = t & 63, wid = t >> 6;
    const float* x = seq + (size_t)row * H_;
    float x0 = x[t], x1 = x[t + 256], x2 = x[t + 512];

    float s = x0 + x1 + x2;
    for (int o = 32; o; o >>= 1) s += __shfl_xor(s, o);
    if (lane == 0) red[wid] = s;
    __syncthreads();
    float mean = (red[0] + red[1] + red[2] + red[3]) * (1.0f / 768.0f);

    float c0 = x0 - mean, c1 = x1 - mean, c2 = x2 - mean;
    float ss = c0 * c0 + c1 * c1 + c2 * c2;
    for (int o = 32; o; o >>= 1) ss += __shfl_xor(ss, o);
    __syncthreads();
    if (lane == 0) red[wid] = ss;
    __syncthreads();
    float var = (red[0] + red[1] + red[2] + red[3]) * (1.0f / 768.0f);
    float sd = var + EPSF;
    float scale = 1.0f / (sd * sd);

    h16* xr = xn + (size_t)row * H_;
    h16* cr = condb + (size_t)row * H_;
    xr[t] = (h16)(c0 * scale); xr[t + 256] = (h16)(c1 * scale); xr[t + 512] = (h16)(c2 * scale);
    cr[t] = (h16)x0;           cr[t + 256] = (h16)x1;           cr[t + 512] = (h16)x2;
}

// ============ kernel B: cond GEMM -> gamma_c / beta_c (f16) ============
// C[p][o] = sum_h cond[p][h] * W[o][h] + bias[o];  tiles 64x64, BK=64
// grid (16, 24): by<12 -> gamma cols by*64 ; else beta cols (by-12)*64
// LDS stride 72 h16 = 144 B: addr%128 takes 8 values over 16 rows -> conflict-free
__global__ __launch_bounds__(256) void k_cond_gemm(
    const h16* __restrict__ Ab, const h16* __restrict__ Wg, const h16* __restrict__ Wb,
    const float* __restrict__ gamma, const float* __restrict__ beta,
    h16* __restrict__ Gc, h16* __restrict__ Bc)
{
    __shared__ h16 Ash[64 * 72];
    __shared__ h16 Bsh[64 * 72];
    const int t = threadIdx.x;
    const int row0 = blockIdx.x * 64;
    const int by = blockIdx.y;
    const bool isg = (by < 12);
    const int nc0 = (isg ? by : by - 12) * 64;
    const h16* wsrc = isg ? Wg : Wb;

    const int r = t >> 2, q = t & 3;
    const h16* ap = Ab + (size_t)(row0 + r) * H_ + q * 16;
    const h16* wp = wsrc + (size_t)(nc0 + r) * H_ + q * 16;
    h16* asto = &Ash[r * 72 + q * 16];
    h16* bsto = &Bsh[r * 72 + q * 16];

    const int lane = t & 63, wid = t >> 6;
    const int wm0 = (wid >> 1) * 32, wn0 = (wid & 1) * 32;
    const int l15 = lane & 15, quad = lane >> 4, q8 = quad * 8;

    typedef float f32x4 __attribute__((ext_vector_type(4)));
    f32x4 acc[2][2] = {};
    for (int kt = 0; kt < 12; ++kt) {
        const int k0 = kt * 64;
        uint4 a0 = *(const uint4*)(ap + k0); uint4 a1 = *(const uint4*)(ap + k0 + 8);
        uint4 w0 = *(const uint4*)(wp + k0); uint4 w1 = *(const uint4*)(wp + k0 + 8);
        *(uint4*)asto = a0; *(uint4*)(asto + 8) = a1;
        *(uint4*)bsto = w0; *(uint4*)(bsto + 8) = w1;
        __syncthreads();
#pragma unroll
        for (int ks = 0; ks < 64; ks += 32) {
            ffrag af[2], bf[2];
#pragma unroll
            for (int mi = 0; mi < 2; ++mi)
                af[mi] = *reinterpret_cast<const ffrag*>(&Ash[(wm0 + mi * 16 + l15) * 72 + ks + q8]);
#pragma unroll
            for (int ni = 0; ni < 2; ++ni)
                bf[ni] = *reinterpret_cast<const ffrag*>(&Bsh[(wn0 + ni * 16 + l15) * 72 + ks + q8]);
#pragma unroll
            for (int mi = 0; mi < 2; ++mi)
#pragma unroll
                for (int ni = 0; ni < 2; ++ni)
                    acc[mi][ni] = __builtin_amdgcn_mfma_f32_16x16x32_f16(af[mi], bf[ni], acc[mi][ni], 0, 0, 0);
        }
        __syncthreads();
    }

    const float* bias = isg ? gamma : beta;
    h16* outp = isg ? Gc : Bc;
#pragma unroll
    for (int mi = 0; mi < 2; ++mi)
#pragma unroll
        for (int ni = 0; ni < 2; ++ni) {
            int c = wn0 + ni * 16 + l15;
            float bv = bias[nc0 + c];
#pragma unroll
            for (int reg = 0; reg < 4; ++reg) {
                int rg = wm0 + mi * 16 + quad * 4 + reg;   // C/D: col=lane&15, row=quad*4+reg (m89)
                outp[(size_t)(row0 + rg) * H_ + nc0 + c] = (h16)(acc[mi][ni][reg] + bv);
            }
        }
}

// ============ kernel C: fused pair GEMM ============
// out[head, gp, m] = tanh( (xn[b,j]*gc[b,i] + bc[b,i]) @ W[:, cg] + biasc[cg] )
// v7: 32x32x16 MFMA + BK=32 + 4 blocks/CU.
// r4 post-mortem ledger: occupancy alone (r1) flat; work-per-barrier (r3)
// flat; counted-vmcnt pipeline (r5) -5%. Only txn coalescing (r2) moved it.
// Residual = latency exposure of the per-iter chain with 2 waves/SIMD.
// Fix here: (1) mfma_f32_32x32x16_f16 halves frag ds_reads (8/iter vs 32)
// and MFMA instr count at same FLOPs; (2) BK=32 -> LDS 32 KB total ->
// launch_bounds(256,4): FOUR barrier-independent blocks/CU (16 waves).
// Sync reverted to v4's plain __syncthreads dbuf (v5's raw-barrier
// pipeline measured worse).  LDS chunk-major slot(ch,row)=(ch*128+row)*8.
__global__ __launch_bounds__(256, 4) void k_pair_gemm(
    const h16* __restrict__ Xn, const h16* __restrict__ Gcb, const h16* __restrict__ Bcb,
    const h16* __restrict__ Wpk, const float* __restrict__ biasc,
    float* __restrict__ out)
{
    __shared__ h16 Ash[2][4 * 128 * 8];   // 8 KB per buf
    __shared__ h16 Bsh[2][4 * 128 * 8];   // 8 KB per buf

    const int t = threadIdx.x;
    const int row0 = blockIdx.x * 128;
    const int nb = blockIdx.y;            // 0..2 -> cols nb*128

    // ---- per-thread staging-row decode (row r_s, k-half `half`) ----
    const int r_s = t >> 1, half = t & 1;
    int gp = row0 + r_s;
    int b = gp / P_;
    int p = gp - b * P_;
    int i = (int)((257.0f - sqrtf(66049.0f - 8.0f * (float)p)) * 0.5f);
    if (i < 0) i = 0; if (i > 127) i = 127;
    while (i > 0 && (i * (257 - i)) / 2 > p) --i;
    while (((i + 1) * (256 - i)) / 2 <= p) ++i;
    int j = i + (p - (i * (257 - i)) / 2);

    const h16* xp  = Xn  + (size_t)(b * 128 + j) * H_ + half * 16;
    const h16* gp_ = Gcb + (size_t)(b * 128 + i) * H_ + half * 16;
    const h16* bp_ = Bcb + (size_t)(b * 128 + i) * H_ + half * 16;
    const int aw0 = ((half * 2 + 0) * 128 + r_s) * 8;
    const int aw1 = ((half * 2 + 1) * 128 + r_s) * 8;

    // B DMA: prepacked tile for (nb,kt) is 4096 h16 contiguous, slot order
    const h16* wtile = Wpk + (size_t)nb * 24 * 4096;
    const int wud = t & ~63;              // wave-uniform slot base

    const int lane = t & 63, wid = t >> 6;
    const int wm0 = (wid >> 1) * 64, wn0 = (wid & 1) * 64;
    const int l31 = lane & 31, hi = lane >> 5;

    // ---------- prologue: stage kt=0 into buffer 0 ----------
#pragma unroll
    for (int c = 0; c < 2; ++c)
        gl_lds16(wtile + (size_t)(c * 256 + t) * 8, &Bsh[0][(c * 256 + wud) * 8]);
    {
        uint4 xa0 = *(const uint4*)xp;       uint4 xa1 = *(const uint4*)(xp + 8);
        uint4 ga0 = *(const uint4*)gp_;      uint4 ga1 = *(const uint4*)(gp_ + 8);
        uint4 ba0 = *(const uint4*)bp_;      uint4 ba1 = *(const uint4*)(bp_ + 8);
        uint4 f0, f1;
        f0.x = fuse2(xa0.x, ga0.x, ba0.x); f0.y = fuse2(xa0.y, ga0.y, ba0.y);
        f0.z = fuse2(xa0.z, ga0.z, ba0.z); f0.w = fuse2(xa0.w, ga0.w, ba0.w);
        f1.x = fuse2(xa1.x, ga1.x, ba1.x); f1.y = fuse2(xa1.y, ga1.y, ba1.y);
        f1.z = fuse2(xa1.z, ga1.z, ba1.z); f1.w = fuse2(xa1.w, ga1.w, ba1.w);
        *(uint4*)&Ash[0][aw0] = f0; *(uint4*)&Ash[0][aw1] = f1;
    }
    __syncthreads();

    f32x16 acc[2][2] = {};
#pragma unroll 2
    for (int kt = 0; kt < 24; ++kt) {
        const int buf = kt & 1, nbf = buf ^ 1;
        uint4 xa0, xa1, ga0, ga1, ba0, ba1;
        if (kt < 23) {
            // next-B DMA first (longest latency), then next-A loads
            const h16* wnext = wtile + (size_t)(kt + 1) * 4096;
#pragma unroll
            for (int c = 0; c < 2; ++c)
                gl_lds16(wnext + (size_t)(c * 256 + t) * 8, &Bsh[nbf][(c * 256 + wud) * 8]);
            const int k0 = (kt + 1) * 32;
            xa0 = *(const uint4*)(xp + k0);  xa1 = *(const uint4*)(xp + k0 + 8);
            ga0 = *(const uint4*)(gp_ + k0); ga1 = *(const uint4*)(gp_ + k0 + 8);
            ba0 = *(const uint4*)(bp_ + k0); ba1 = *(const uint4*)(bp_ + k0 + 8);
        }

#pragma unroll
        for (int ks = 0; ks < 2; ++ks) {
            const int ch0 = ks * 2;           // k-window ks*16 -> chunks ch0, ch0+1
            ffrag af[2], bf[2];
#pragma unroll
            for (int mi = 0; mi < 2; ++mi)
                af[mi] = *reinterpret_cast<const ffrag*>(
                    &Ash[buf][((ch0 + hi) * 128 + wm0 + mi * 32 + l31) * 8]);
#pragma unroll
            for (int ni = 0; ni < 2; ++ni)
                bf[ni] = *reinterpret_cast<const ffrag*>(
                    &Bsh[buf][((ch0 + hi) * 128 + wn0 + ni * 32 + l31) * 8]);
#pragma unroll
            for (int mi = 0; mi < 2; ++mi)
#pragma unroll
                for (int ni = 0; ni < 2; ++ni)
                    acc[mi][ni] = __builtin_amdgcn_mfma_f32_32x32x16_f16(af[mi], bf[ni], acc[mi][ni], 0, 0, 0);
        }

        if (kt < 23) {
            uint4 f0, f1;
            f0.x = fuse2(xa0.x, ga0.x, ba0.x); f0.y = fuse2(xa0.y, ga0.y, ba0.y);
            f0.z = fuse2(xa0.z, ga0.z, ba0.z); f0.w = fuse2(xa0.w, ga0.w, ba0.w);
            f1.x = fuse2(xa1.x, ga1.x, ba1.x); f1.y = fuse2(xa1.y, ga1.y, ba1.y);
            f1.z = fuse2(xa1.z, ga1.z, ba1.z); f1.w = fuse2(xa1.w, ga1.w, ba1.w);
            *(uint4*)&Ash[nbf][aw0] = f0; *(uint4*)&Ash[nbf][aw1] = f1;
        }
        __syncthreads();
    }

    // epilogue: bias + tanh + store (head == nb, m == col, since BN=128)
    // C/D 32x32: col = lane&31, row = (reg&3) + 8*(reg>>2) + 4*(lane>>5)  [m74/m101]
#pragma unroll
    for (int mi = 0; mi < 2; ++mi)
#pragma unroll
        for (int ni = 0; ni < 2; ++ni) {
            int c = wn0 + ni * 32 + l31;
            float bv = biasc[nb * 128 + c];
#pragma unroll
            for (int reg = 0; reg < 16; ++reg) {
                int rg = wm0 + mi * 32 + (reg & 3) + 8 * (reg >> 2) + 4 * hi;
                out[((size_t)nb * BP_ + row0 + rg) * M_ + c] = fast_tanh(acc[mi][ni][reg] + bv);
            }
        }
}

extern "C" void kernel_launch(void* const* d_in, const int* in_sizes, int n_in,
                              void* d_out, int out_size, void* d_ws, size_t ws_size,
                              hipStream_t stream)
{
    const float* seq     = (const float*)d_in[0];
    const float* gamma   = (const float*)d_in[1];
    const float* beta    = (const float*)d_in[2];
    const float* w_beta  = (const float*)d_in[3];
    const float* w_gamma = (const float*)d_in[4];
    const float* w_ent   = (const float*)d_in[5];
    const float* b_ent   = (const float*)d_in[6];
    const float* w_head  = (const float*)d_in[7];
    const float* b_head  = (const float*)d_in[8];
    const float* w_tail  = (const float*)d_in[9];
    const float* b_tail  = (const float*)d_in[10];
    float* out = (float*)d_out;

    // workspace layout (all 16B-aligned)
    char* ws = (char*)d_ws;
    h16* xn    = (h16*)ws; ws += (size_t)1024 * 768 * 2;  // normalized rows, f16
    h16* condb = (h16*)ws; ws += (size_t)1024 * 768 * 2;  // seq as f16
    h16* wgb   = (h16*)ws; ws += (size_t)768 * 768 * 2;   // w_gamma f16 [o][h]
    h16* wbb   = (h16*)ws; ws += (size_t)768 * 768 * 2;   // w_beta  f16 [o][h]
    h16* wpk   = (h16*)ws; ws += (size_t)294912 * 2;      // pre-packed B tiles (3 x 24 x 8KB)
    h16* gc    = (h16*)ws; ws += (size_t)1024 * 768 * 2;  // gamma_c f16
    h16* bc    = (h16*)ws; ws += (size_t)1024 * 768 * 2;  // beta_c  f16
    float* biasc = (float*)ws; ws += 384 * 4;             // [ent|head|tail] bias

    hipLaunchKernelGGL(k_prep, dim3(NORM0 + 1024), dim3(256), 0, stream,
                       seq, w_gamma, w_beta, w_ent, w_head, w_tail,
                       b_ent, b_head, b_tail, wgb, wbb, wpk, biasc, xn, condb);
    hipLaunchKernelGGL(k_cond_gemm, dim3(16, 24), dim3(256), 0, stream,
                       condb, wgb, wbb, gamma, beta, gc, bc);
    hipLaunchKernelGGL(k_pair_gemm, dim3(516, 3), dim3(256), 0, stream,
                       xn, gc, bc, wpk, biasc, out);
}